// Round 1
// baseline (67.861 us; speedup 1.0000x reference)
//
#include <hip/hip_runtime.h>
#include <math.h>

#define QROWS 256
#define RT    28528
#define TOTAL (QROWS + 2 * RT)   // 57312 rows, 16 floats each

__global__ __launch_bounds__(256) void head_kernel(
    const float* __restrict__ x,   // (1,16,16,16)  [t][H][W]
    const float* __restrict__ Wq,  // (16,16)
    const float* __restrict__ Wk,  // (16,16,16)
    const float* __restrict__ bk,  // (16,16)
    const float* __restrict__ Wv,  // (16,16,16)
    const float* __restrict__ bv,  // (16,16)
    float* __restrict__ out)       // (57312,16)
{
    __shared__ float sx[4096];
    __shared__ float sWq[256];
    __shared__ float sWk[4096];
    __shared__ float sWv[4096];
    __shared__ float sb[512];      // bk then bv

    const int tid = threadIdx.x;
    #pragma unroll
    for (int it = 0; it < 16; ++it) {
        int idx = tid + it * 256;
        sx[idx]  = x[idx];
        sWk[idx] = Wk[idx];
        sWv[idx] = Wv[idx];
    }
    sWq[tid]      = Wq[tid];
    sb[tid]       = bk[tid];
    sb[256 + tid] = bv[tid];
    __syncthreads();

    const int r = blockIdx.x * 256 + tid;
    if (r >= TOTAL) return;

    // cumulative row offsets of the 16 time-groups (R(g) = 16*(g+2)^2 - 1)
    const int OFF[17] = {0, 63, 206, 461, 860, 1435, 2218, 3241, 4536, 6135,
                         8070, 10373, 13076, 16211, 19810, 23905, 28528};

    int n, c;                      // patch index, channel index into x
    const float* Wmat;             // 16x16 weight (LDS)
    const float* bvec;             // 16 bias (LDS), scaled by bscale
    float bscale;

    if (r < QROWS) {
        n = r >> 4;
        c = r & 15;
        Wmat = sWq;
        bvec = sb;                 // valid address, zeroed by bscale
        bscale = 0.0f;
    } else {
        int rr = r - QROWS;
        int sec = 0;
        if (rr >= RT) { rr -= RT; sec = 1; }

        int g = 0;
        #pragma unroll
        for (int gg = 1; gg < 16; ++gg) g += (rr >= OFF[gg]) ? 1 : 0;
        const int pos = rr - OFF[g];
        const int T = g + 1;
        const int L = (T + 1) * (T + 1);

        int j, p;
        if (pos < L - 1) { j = 0; p = pos; }
        else             { j = (pos + 1) / L; p = (pos + 1) - j * L; }

        int timev, pat;
        if (p == 0) {
            timev = T - 1; pat = j;            // header entry (T-1, j)
        } else {
            int q = p - 1 + ((j == 0) ? 1 : 0); // j==0: skip excluded (i=2,l=0)
            int v = q + 1;                      // generic position + 1
            int s = (int)sqrtf((float)v);
            if (s * s > v) --s;
            if ((s + 1) * (s + 1) <= v) ++s;    // s = floor(sqrt(v))
            const int i = s + 1;                // block index (2..T+1)
            const int m = v - s * s;            // position within block
            timev = T + 1 - i;
            int cm = i + j - 16; if (cm < 0) cm = 0;   // count of k=-1 entries
            if (m < cm) {
                pat = m;                                // k=-1: idx = m
            } else {
                const int m2 = m - cm;
                const int lo0 = (1 - i > -j) ? (1 - i) : (-j);
                const int hi0 = (i - 1 < 15 - j) ? (i - 1) : (15 - j);
                const int c0 = hi0 - lo0 + 1;
                if (m2 < c0) pat = j + lo0 + m2;        // k=0 band
                else         pat = j + 17 - i + (m2 - c0); // k=+1 band
            }
        }
        // raw-reshape scrambling: flat F over (time,pat) -> (patch n, channel c)
        const int F = timev * 16 + pat;
        n = F / T;
        c = F - n * T;
        Wmat = (sec ? sWv : sWk) + g * 256;
        bvec = sb + (sec ? 256 : 0) + g * 16;
        bscale = 1.0f;
    }

    // gather the 16 pixels of patch n, channel c
    const int base = c * 256 + ((n >> 2) << 6) + ((n & 3) << 2);
    float xr[16];
    #pragma unroll
    for (int pr = 0; pr < 4; ++pr) {
        const float4 v4 = *(const float4*)&sx[base + pr * 16];
        xr[pr * 4 + 0] = v4.x; xr[pr * 4 + 1] = v4.y;
        xr[pr * 4 + 2] = v4.z; xr[pr * 4 + 3] = v4.w;
    }

    float o[16];
    #pragma unroll
    for (int e = 0; e < 16; ++e) {
        float acc = bvec[e] * bscale;
        #pragma unroll
        for (int q = 0; q < 16; ++q) acc += xr[q] * Wmat[e * 16 + q];
        o[e] = acc;
    }

    float4* op = (float4*)(out + (size_t)r * 16);
    op[0] = *(float4*)&o[0];
    op[1] = *(float4*)&o[4];
    op[2] = *(float4*)&o[8];
    op[3] = *(float4*)&o[12];
}

extern "C" void kernel_launch(void* const* d_in, const int* in_sizes, int n_in,
                              void* d_out, int out_size, void* d_ws, size_t ws_size,
                              hipStream_t stream) {
    (void)in_sizes; (void)n_in; (void)d_ws; (void)ws_size; (void)out_size;
    const float* x  = (const float*)d_in[0];
    const float* Wq = (const float*)d_in[1];
    const float* Wk = (const float*)d_in[2];
    const float* bk = (const float*)d_in[3];
    const float* Wv = (const float*)d_in[4];
    const float* bv = (const float*)d_in[5];
    float* out = (float*)d_out;
    const int blocks = (TOTAL + 255) / 256;   // 224
    head_kernel<<<blocks, 256, 0, stream>>>(x, Wq, Wk, bk, Wv, bv, out);
}